// Round 13
// baseline (698.226 us; speedup 1.0000x reference)
//
#include <hip/hip_runtime.h>
#include <math.h>

#define NNODES 50000
#define NEG_SLOPE 0.2f
#define BN_EPS 1e-5f

typedef __attribute__((ext_vector_type(8))) short bf16x8;
typedef __attribute__((ext_vector_type(4))) float f32x4;

static __device__ __forceinline__ float leaky(float x) {
    return x > 0.f ? x : NEG_SLOPE * x;
}
static __device__ __forceinline__ unsigned short f2bf(float x) {
    unsigned u = __float_as_uint(x);
    u += 0x7FFFu + ((u >> 16) & 1u);
    return (unsigned short)(u >> 16);
}
static __device__ __forceinline__ void unpack8(uint4 u, float* v) {
    v[0] = __uint_as_float(u.x << 16);
    v[1] = __uint_as_float(u.x & 0xFFFF0000u);
    v[2] = __uint_as_float(u.y << 16);
    v[3] = __uint_as_float(u.y & 0xFFFF0000u);
    v[4] = __uint_as_float(u.z << 16);
    v[5] = __uint_as_float(u.z & 0xFFFF0000u);
    v[6] = __uint_as_float(u.w << 16);
    v[7] = __uint_as_float(u.w & 0xFFFF0000u);
}
static __device__ __forceinline__ void acc8(uint4 u, float w, float* a) {
    float v[8]; unpack8(u, v);
#pragma unroll
    for (int j = 0; j < 8; ++j) a[j] = fmaf(w, v[j], a[j]);
}
static __device__ __forceinline__ void add8(uint4 u, float* a) {
    float v[8]; unpack8(u, v);
#pragma unroll
    for (int j = 0; j < 8; ++j) a[j] += v[j];
}
static __device__ __forceinline__ uint4 pack8(const float* o) {
    uint4 r;
    r.x = ((unsigned)f2bf(o[1]) << 16) | f2bf(o[0]);
    r.y = ((unsigned)f2bf(o[3]) << 16) | f2bf(o[2]);
    r.z = ((unsigned)f2bf(o[5]) << 16) | f2bf(o[4]);
    r.w = ((unsigned)f2bf(o[7]) << 16) | f2bf(o[6]);
    return r;
}

// ---------------- CSR build ----------------
__global__ void k_count(const int* __restrict__ dst, int* degi, int E) {
    int e = blockIdx.x * blockDim.x + threadIdx.x;
    if (e < E) atomicAdd(&degi[dst[e]], 1);
}
__global__ void k_scan1(const int* __restrict__ degi, int* __restrict__ incl,
                        int* __restrict__ bsum, int n) {
    __shared__ int s[256];
    int i = blockIdx.x * 256 + threadIdx.x;
    int v = (i < n) ? degi[i] : 0;
    s[threadIdx.x] = v;
    __syncthreads();
    for (int off = 1; off < 256; off <<= 1) {
        int t = (threadIdx.x >= (unsigned)off) ? s[threadIdx.x - off] : 0;
        __syncthreads();
        s[threadIdx.x] += t;
        __syncthreads();
    }
    if (i < n) incl[i] = s[threadIdx.x];
    if (threadIdx.x == 255) bsum[blockIdx.x] = s[255];
}
__global__ void k_scan2(int* bsum, int nb) {
    __shared__ int s[256];
    int v = ((int)threadIdx.x < nb) ? bsum[threadIdx.x] : 0;
    s[threadIdx.x] = v;
    __syncthreads();
    for (int off = 1; off < 256; off <<= 1) {
        int t = (threadIdx.x >= (unsigned)off) ? s[threadIdx.x - off] : 0;
        __syncthreads();
        s[threadIdx.x] += t;
        __syncthreads();
    }
    if ((int)threadIdx.x < nb) bsum[threadIdx.x] = s[threadIdx.x];
}
__global__ void k_scan3(const int* __restrict__ degi, const int* __restrict__ incl,
                        const int* __restrict__ bsum, int* __restrict__ row_ptr,
                        int* __restrict__ cursor, float* __restrict__ dinv, int n) {
    int i = blockIdx.x * 256 + threadIdx.x;
    if (i >= n) return;
    int off = (blockIdx.x > 0) ? bsum[blockIdx.x - 1] : 0;
    int inc = incl[i] + off;
    row_ptr[i + 1] = inc;
    cursor[i] = inc - degi[i];
    dinv[i] = rsqrtf((float)(degi[i] + 1));
    if (i == 0) row_ptr[0] = 0;
}
__global__ void k_fill(const int* __restrict__ src, const int* __restrict__ dst,
                       int* cursor, int* __restrict__ csr_src, int E) {
    int e = blockIdx.x * blockDim.x + threadIdx.x;
    if (e >= E) return;
    int pos = atomicAdd(&cursor[dst[e]], 1);
    csr_src[pos] = src[e];
}

// ---------------- degree-sorted node permutation (counting sort, 64 buckets) ----------------
__global__ void k_hist(const int* __restrict__ degi, int* hcnt, int n) {
    int v = blockIdx.x * blockDim.x + threadIdx.x;
    if (v < n) atomicAdd(&hcnt[min(degi[v], 63)], 1);
}
__global__ void k_hscan(const int* __restrict__ hcnt, int* __restrict__ hbase) {
    // single block of 64 threads: exclusive scan of 64 bins
    __shared__ int s[64];
    int t = threadIdx.x;
    s[t] = hcnt[t];
    __syncthreads();
    for (int off = 1; off < 64; off <<= 1) {
        int x = (t >= off) ? s[t - off] : 0;
        __syncthreads();
        s[t] += x;
        __syncthreads();
    }
    hbase[t] = s[t] - hcnt[t];  // exclusive
}
__global__ void k_permfill(const int* __restrict__ degi, int* hbase,
                           int* __restrict__ perm, int n) {
    int v = blockIdx.x * blockDim.x + threadIdx.x;
    if (v >= n) return;
    int pos = atomicAdd(&hbase[min(degi[v], 63)], 1);
    perm[pos] = v;
}

// ---------------- fused conversions: x -> bf16, 4 weights -> bf16 transposed ----------------
__global__ void k_convall(const float4* __restrict__ x, uint4* __restrict__ xout,
                          const float* __restrict__ W1, unsigned short* __restrict__ w1T,
                          const float* __restrict__ W2, unsigned short* __restrict__ w2T,
                          const float* __restrict__ W3, unsigned short* __restrict__ w3T,
                          const float* __restrict__ W4, unsigned short* __restrict__ w4T,
                          int nx) {
    int i = blockIdx.x * blockDim.x + threadIdx.x;
    if (i < nx) {
        float4 a = x[i * 2], b = x[i * 2 + 1];
        float o[8] = {a.x, a.y, a.z, a.w, b.x, b.y, b.z, b.w};
        xout[i] = pack8(o);
        return;
    }
    int j = i - nx;
    if (j < 12288) {                       // W1 128x96
        int k = j / 96, c = j % 96;
        w1T[c * 128 + k] = f2bf(W1[j]);
    } else if ((j -= 12288) < 18432) {     // W2 96x192
        int k = j / 192, c = j % 192;
        w2T[c * 96 + k] = f2bf(W2[j]);
    } else if ((j -= 18432) < 9216) {      // W3 96x96
        int k = j / 96, c = j % 96;
        w3T[c * 96 + k] = f2bf(W3[j]);
    } else if ((j -= 9216) < 7680) {       // W4 96x80
        int k = j / 80, c = j % 80;
        w4T[c * 96 + k] = f2bf(W4[j]);
    }
}

// ---------------- MFMA bf16 GEMM ----------------
// HC>0: fused GAT logits epilogue. SCALE: multiply output row by dinv[row] (GCN pre-scale).
template<int KI, int KO, int HC, int SCALE>
__launch_bounds__(256)
__global__ void k_gemm_mfma(const unsigned short* __restrict__ A,
                            const unsigned short* __restrict__ WT,
                            unsigned short* __restrict__ C, int n,
                            const float* __restrict__ as, const float* __restrict__ ad,
                            float* __restrict__ alS, float* __restrict__ alD,
                            const float* __restrict__ dinv) {
    constexpr int KP = KI + 8;
    constexpr int NT = KO / 16;
    constexpr int KT = KI / 32;
    __shared__ unsigned short wT[KO][KP];
    const int t = threadIdx.x;
    const int w = t >> 6, l = t & 63;

    constexpr int CH = KI / 8;
    for (int idx = t; idx < KO * CH; idx += 256) {
        int r = idx / CH, o = idx % CH;
        *(uint4*)&wT[r][o * 8] = *(const uint4*)&WT[r * KI + o * 8];
    }
    int row = blockIdx.x * 64 + w * 16 + (l & 15);
    bool rv = row < n;
    const unsigned short* ap = A + (long long)row * KI + (l >> 4) * 8;
    bf16x8 afr[KT];
#pragma unroll
    for (int kt = 0; kt < KT; ++kt) {
        bf16x8 z = {};
        afr[kt] = rv ? *(const bf16x8*)(ap + kt * 32) : z;
    }
    __syncthreads();

    f32x4 acc[NT];
#pragma unroll
    for (int ct = 0; ct < NT; ++ct) acc[ct] = (f32x4){0.f, 0.f, 0.f, 0.f};
#pragma unroll
    for (int kt = 0; kt < KT; ++kt) {
#pragma unroll
        for (int ct = 0; ct < NT; ++ct) {
            bf16x8 b = *(const bf16x8*)&wT[ct * 16 + (l & 15)][kt * 32 + (l >> 4) * 8];
            acc[ct] = __builtin_amdgcn_mfma_f32_16x16x32_bf16(afr[kt], b, acc[ct], 0, 0, 0);
        }
    }
    int orow0 = blockIdx.x * 64 + w * 16 + (l >> 4) * 4;
    int col = l & 15;
    float dsc[4] = {1.f, 1.f, 1.f, 1.f};
    if (SCALE) {
#pragma unroll
        for (int r = 0; r < 4; ++r) {
            int rr = orow0 + r;
            if (rr < n) dsc[r] = dinv[rr];
        }
    }
#pragma unroll
    for (int ct = 0; ct < NT; ++ct) {
#pragma unroll
        for (int r = 0; r < 4; ++r) {
            int rr = orow0 + r;
            if (rr < n) C[(long long)rr * KO + ct * 16 + col] = f2bf(acc[ct][r] * dsc[r]);
        }
    }
    if (HC > 0) {
        float asv[NT], adv[NT];
#pragma unroll
        for (int ct = 0; ct < NT; ++ct) {
            int cg = ct * 16 + col;
            asv[ct] = as[cg];
            adv[ct] = ad[cg];
        }
#pragma unroll
        for (int r = 0; r < 4; ++r) {
            float s0 = 0.f, s1 = 0.f, d0 = 0.f, d1 = 0.f;
#pragma unroll
            for (int ct = 0; ct < NT; ++ct) {
                int cg = ct * 16 + col;
                float v = acc[ct][r];
                if (cg < HC) { s0 = fmaf(v, asv[ct], s0); d0 = fmaf(v, adv[ct], d0); }
                else         { s1 = fmaf(v, asv[ct], s1); d1 = fmaf(v, adv[ct], d1); }
            }
#pragma unroll
            for (int m = 1; m < 16; m <<= 1) {
                s0 += __shfl_xor(s0, m);
                s1 += __shfl_xor(s1, m);
                d0 += __shfl_xor(d0, m);
                d1 += __shfl_xor(d1, m);
            }
            int rr = orow0 + r;
            if ((l & 15) == 0 && rr < n) {
                alS[rr * 2] = s0; alS[rr * 2 + 1] = s1;
                alD[rr * 2] = d0; alD[rr * 2 + 1] = d1;
            }
        }
    }
}

// ---------------- GCN gather (pre-scaled table, degree-sorted perm) ----------------
__global__ void k_gcn_gather_bn8(const uint4* __restrict__ hb, const int* __restrict__ row_ptr,
                                 const int* __restrict__ csr_src, const int* __restrict__ perm,
                                 const float* __restrict__ dinv,
                                 const float* __restrict__ bias, const float* __restrict__ g,
                                 const float* __restrict__ b, const float* __restrict__ m,
                                 const float* __restrict__ vv,
                                 uint4* __restrict__ outb, int n, int Q8) {
    int t = blockIdx.x * blockDim.x + threadIdx.x;
    if (t >= n * Q8) return;
    int v = perm[t / Q8], q = t % Q8;
    int beg = row_ptr[v], end = row_ptr[v + 1];
    float dv = dinv[v];
    float a[8] = {0.f, 0.f, 0.f, 0.f, 0.f, 0.f, 0.f, 0.f};
    add8(hb[(long long)v * Q8 + q], a);  // self term (table pre-scaled by dinv)
    int p = beg;
    for (; p + 4 <= end; p += 4) {
        int s0 = csr_src[p], s1 = csr_src[p + 1], s2 = csr_src[p + 2], s3 = csr_src[p + 3];
        uint4 u0 = hb[(long long)s0 * Q8 + q];
        uint4 u1 = hb[(long long)s1 * Q8 + q];
        uint4 u2 = hb[(long long)s2 * Q8 + q];
        uint4 u3 = hb[(long long)s3 * Q8 + q];
        add8(u0, a);
        add8(u1, a);
        add8(u2, a);
        add8(u3, a);
    }
    for (; p < end; ++p) {
        int s = csr_src[p];
        add8(hb[(long long)s * Q8 + q], a);
    }
    int c0 = q * 8;
    float o[8];
#pragma unroll
    for (int j = 0; j < 8; ++j) {
        int c = c0 + j;
        float x = fmaf(a[j], dv, bias[c]);
        x = (x - m[c]) * rsqrtf(vv[c] + BN_EPS) * g[c] + b[c];
        o[j] = fmaxf(x, 0.f);
    }
    outb[(long long)v * Q8 + q] = pack8(o);
}

// ---------------- GAT softmax (two-pass, per node, both heads, perm) ----------------
__global__ void k_gat_vh2p(const int* __restrict__ row_ptr, const int* __restrict__ csr_src,
                           const int* __restrict__ perm,
                           const float2* __restrict__ alS2, const float2* __restrict__ alD2,
                           float2* __restrict__ eex2, float2* __restrict__ selfw2,
                           float2* __restrict__ invden2, int n) {
    int i = blockIdx.x * blockDim.x + threadIdx.x;
    if (i >= n) return;
    int v = perm[i];
    int beg = row_ptr[v], end = row_ptr[v + 1];
    float2 ad = alD2[v], as0 = alS2[v];
    float ls0 = leaky(as0.x + ad.x), ls1 = leaky(as0.y + ad.y);
    float m0 = ls0, m1 = ls1;
    int p = beg;
    for (; p + 2 <= end; p += 2) {
        int s0 = csr_src[p], s1 = csr_src[p + 1];
        float2 a0 = alS2[s0], a1 = alS2[s1];
        float l00 = leaky(a0.x + ad.x), l01 = leaky(a0.y + ad.y);
        float l10 = leaky(a1.x + ad.x), l11 = leaky(a1.y + ad.y);
        eex2[p] = make_float2(l00, l01);
        eex2[p + 1] = make_float2(l10, l11);
        m0 = fmaxf(m0, fmaxf(l00, l10));
        m1 = fmaxf(m1, fmaxf(l01, l11));
    }
    if (p < end) {
        int s = csr_src[p];
        float2 a = alS2[s];
        float l0 = leaky(a.x + ad.x), l1 = leaky(a.y + ad.y);
        eex2[p] = make_float2(l0, l1);
        m0 = fmaxf(m0, l0);
        m1 = fmaxf(m1, l1);
    }
    float e0 = expf(ls0 - m0), e1 = expf(ls1 - m1);
    float d0 = e0, d1 = e1;
    for (p = beg; p < end; ++p) {
        float2 l = eex2[p];
        float x0 = expf(l.x - m0), x1 = expf(l.y - m1);
        eex2[p] = make_float2(x0, x1);
        d0 += x0; d1 += x1;
    }
    selfw2[v] = make_float2(e0, e1);
    invden2[v] = make_float2(1.f / d0, 1.f / d1);
}
// ---------------- GAT gather (bf16, 4-edge unrolled, perm) ----------------
template<int OUTBF>
__global__ void k_gat_gather2_8(const uint4* __restrict__ hb, const int* __restrict__ row_ptr,
                                const int* __restrict__ csr_src, const int* __restrict__ perm,
                                const float2* __restrict__ eex2,
                                const float2* __restrict__ selfw2, const float2* __restrict__ invden2,
                                const float* __restrict__ bias, uint4* __restrict__ outb,
                                float4* __restrict__ outf, int n, int Q8, int do_relu) {
    int t = blockIdx.x * blockDim.x + threadIdx.x;
    if (t >= n * Q8) return;
    int v = perm[t / Q8], q = t % Q8;
    int rowOct = 2 * Q8;
    int beg = row_ptr[v], end = row_ptr[v + 1];
    float A0[8] = {0,0,0,0,0,0,0,0}, A1[8] = {0,0,0,0,0,0,0,0};
    {
        float2 sw = selfw2[v];
        const uint4* hv = hb + (long long)v * rowOct;
        acc8(hv[q], sw.x, A0);
        acc8(hv[Q8 + q], sw.y, A1);
    }
    int p = beg;
    for (; p + 4 <= end; p += 4) {
        int s0 = csr_src[p], s1 = csr_src[p + 1], s2 = csr_src[p + 2], s3 = csr_src[p + 3];
        float2 w0 = eex2[p], w1 = eex2[p + 1], w2 = eex2[p + 2], w3 = eex2[p + 3];
        const uint4* h0 = hb + (long long)s0 * rowOct;
        const uint4* h1 = hb + (long long)s1 * rowOct;
        const uint4* h2 = hb + (long long)s2 * rowOct;
        const uint4* h3 = hb + (long long)s3 * rowOct;
        uint4 u00 = h0[q], u01 = h0[Q8 + q];
        uint4 u10 = h1[q], u11 = h1[Q8 + q];
        uint4 u20 = h2[q], u21 = h2[Q8 + q];
        uint4 u30 = h3[q], u31 = h3[Q8 + q];
        acc8(u00, w0.x, A0); acc8(u01, w0.y, A1);
        acc8(u10, w1.x, A0); acc8(u11, w1.y, A1);
        acc8(u20, w2.x, A0); acc8(u21, w2.y, A1);
        acc8(u30, w3.x, A0); acc8(u31, w3.y, A1);
    }
    for (; p < end; ++p) {
        int s = csr_src[p];
        float2 w = eex2[p];
        const uint4* hs = hb + (long long)s * rowOct;
        acc8(hs[q], w.x, A0);
        acc8(hs[Q8 + q], w.y, A1);
    }
    float2 idn = invden2[v];
    int c0 = q * 8;
    float o[8];
#pragma unroll
    for (int j = 0; j < 8; ++j) {
        float x = fmaf(0.5f, fmaf(A0[j], idn.x, A1[j] * idn.y), bias[c0 + j]);
        o[j] = do_relu ? fmaxf(x, 0.f) : x;
    }
    if (OUTBF) {
        outb[(long long)v * Q8 + q] = pack8(o);
    } else {
        long long ob = (long long)v * (Q8 * 2) + q * 2;
        outf[ob]     = make_float4(o[0], o[1], o[2], o[3]);
        outf[ob + 1] = make_float4(o[4], o[5], o[6], o[7]);
    }
}

__global__ void k_logsoftmax40(const float* __restrict__ in, float* __restrict__ out, int n) {
    int v = blockIdx.x * blockDim.x + threadIdx.x;
    if (v >= n) return;
    float vals[40];
    float mx = -INFINITY;
#pragma unroll
    for (int c = 0; c < 40; ++c) {
        float x = in[v * 40 + c];
        vals[c] = x;
        mx = fmaxf(mx, x);
    }
    float s = 0.f;
#pragma unroll
    for (int c = 0; c < 40; ++c) s += expf(vals[c] - mx);
    float ls = logf(s);
#pragma unroll
    for (int c = 0; c < 40; ++c) out[v * 40 + c] = vals[c] - mx - ls;
}

static inline int nblk(long long n, int b) { return (int)((n + b - 1) / b); }

extern "C" void kernel_launch(void* const* d_in, const int* in_sizes, int n_in,
                              void* d_out, int out_size, void* d_ws, size_t ws_size,
                              hipStream_t stream) {
    const float* x       = (const float*)d_in[0];
    const int*   ei      = (const int*)d_in[1];
    const float* gcn1_W  = (const float*)d_in[2];
    const float* gcn1_b  = (const float*)d_in[3];
    const float* bn1_g   = (const float*)d_in[4];
    const float* bn1_b   = (const float*)d_in[5];
    const float* bn1_m   = (const float*)d_in[6];
    const float* bn1_v   = (const float*)d_in[7];
    const float* gat1_W  = (const float*)d_in[8];
    const float* gat1_as = (const float*)d_in[9];
    const float* gat1_ad = (const float*)d_in[10];
    const float* gat1_b  = (const float*)d_in[11];
    const float* gcn2_W  = (const float*)d_in[12];
    const float* gcn2_b  = (const float*)d_in[13];
    const float* bn2_g   = (const float*)d_in[14];
    const float* bn2_b   = (const float*)d_in[15];
    const float* bn2_m   = (const float*)d_in[16];
    const float* bn2_v   = (const float*)d_in[17];
    const float* gat2_W  = (const float*)d_in[18];
    const float* gat2_as = (const float*)d_in[19];
    const float* gat2_ad = (const float*)d_in[20];
    const float* gat2_b  = (const float*)d_in[21];

    const int n = NNODES;
    const int E = in_sizes[1] / 2;
    const int* src = ei;
    const int* dst = ei + E;

    // ---- workspace carve (16B-aligned chunks) ----
    char* p = (char*)d_ws;
    float* dinv    = (float*)p; p += 50048 * 4;
    int*   degi    = (int*)p;   p += 50048 * 4;
    int*   row_ptr = (int*)p;   p += 50052 * 4;
    int*   cursor  = (int*)p;   p += 50048 * 4;
    int*   incl    = (int*)p;   p += 50048 * 4;
    int*   bsum    = (int*)p;   p += 256 * 4;
    int*   perm    = (int*)p;   p += 50048 * 4;
    int*   hcnt    = (int*)p;   p += 64 * 4;
    int*   hbase   = (int*)p;   p += 64 * 4;
    int*   csr_src = (int*)p;   p += 800000 * 4;
    unsigned short* hbf = (unsigned short*)p; p += 9600000 * 2;  // bf16 h table [N,<=192]
    unsigned short* abf = (unsigned short*)p; p += 6400000 * 2;  // bf16 activations [N,<=128]
    unsigned short* wbf = (unsigned short*)p; p += 47616 * 2 + 64; // bf16 WT arena
    float* bufA    = (float*)p; p += 2000000 * 4;                // f32 gat2 out [N,40]
    float* alS     = (float*)p; p += 100096 * 4;
    float* alD     = (float*)p; p += 100096 * 4;
    float* selfw   = (float*)p; p += 100096 * 4;
    float* invden  = (float*)p; p += 100096 * 4;
    float* eex     = (float*)p; p += 1600000 * 4;                // float2[E]

    unsigned short* w1T = wbf;                 // [96][128]
    unsigned short* w2T = wbf + 12288;         // [192][96]
    unsigned short* w3T = wbf + 12288 + 18432; // [96][96]
    unsigned short* w4T = wbf + 12288 + 18432 + 9216; // [80][96]

    const int B = 256;
    const int GB = nblk(n, 64);
    const int SB = nblk(n, 256);
    float* out = (float*)d_out;

    // ---- fused conversions (x + 4 weights) ----
    const int NX = n * 16;
    k_convall<<<nblk(NX + 47616, B), B, 0, stream>>>(
        (const float4*)x, (uint4*)abf, gcn1_W, w1T, gat1_W, w2T, gcn2_W, w3T, gat2_W, w4T, NX);

    // ---- CSR build + degree-sorted perm ----
    hipMemsetAsync(degi, 0, (size_t)n * 4, stream);
    hipMemsetAsync(hcnt, 0, 64 * 4, stream);
    k_count<<<nblk(E, B), B, 0, stream>>>(dst, degi, E);
    k_scan1<<<SB, 256, 0, stream>>>(degi, incl, bsum, n);
    k_scan2<<<1, 256, 0, stream>>>(bsum, SB);
    k_scan3<<<SB, 256, 0, stream>>>(degi, incl, bsum, row_ptr, cursor, dinv, n);
    k_fill<<<nblk(E, B), B, 0, stream>>>(src, dst, cursor, csr_src, E);
    k_hist<<<nblk(n, B), B, 0, stream>>>(degi, hcnt, n);
    k_hscan<<<1, 64, 0, stream>>>(hcnt, hbase);
    k_permfill<<<nblk(n, B), B, 0, stream>>>(degi, hbase, perm, n);

    // ---- GCN1 (GEMM pre-scales rows by dinv; gather is pure sum) ----
    k_gemm_mfma<128, 96, 0, 1><<<GB, 256, 0, stream>>>(abf, w1T, hbf, n, nullptr, nullptr,
                                                       nullptr, nullptr, dinv);
    k_gcn_gather_bn8<<<nblk((long long)n * 12, B), B, 0, stream>>>(
        (const uint4*)hbf, row_ptr, csr_src, perm, dinv, gcn1_b, bn1_g, bn1_b, bn1_m, bn1_v,
        (uint4*)abf, n, 12);

    // ---- GAT1 (logits fused into GEMM epilogue) ----
    k_gemm_mfma<96, 192, 96, 0><<<GB, 256, 0, stream>>>(abf, w2T, hbf, n, gat1_as, gat1_ad,
                                                        alS, alD, nullptr);
    k_gat_vh2p<<<nblk(n, B), B, 0, stream>>>(row_ptr, csr_src, perm, (const float2*)alS,
                                             (const float2*)alD, (float2*)eex, (float2*)selfw,
                                             (float2*)invden, n);
    k_gat_gather2_8<1><<<nblk((long long)n * 12, B), B, 0, stream>>>(
        (const uint4*)hbf, row_ptr, csr_src, perm, (const float2*)eex, (const float2*)selfw,
        (const float2*)invden, gat1_b, (uint4*)abf, nullptr, n, 12, 1);

    // ---- GCN2 ----
    k_gemm_mfma<96, 96, 0, 1><<<GB, 256, 0, stream>>>(abf, w3T, hbf, n, nullptr, nullptr,
                                                      nullptr, nullptr, dinv);
    k_gcn_gather_bn8<<<nblk((long long)n * 12, B), B, 0, stream>>>(
        (const uint4*)hbf, row_ptr, csr_src, perm, dinv, gcn2_b, bn2_g, bn2_b, bn2_m, bn2_v,
        (uint4*)abf, n, 12);

    // ---- GAT2 (logits fused) ----
    k_gemm_mfma<96, 80, 40, 0><<<GB, 256, 0, stream>>>(abf, w4T, hbf, n, gat2_as, gat2_ad,
                                                       alS, alD, nullptr);
    k_gat_vh2p<<<nblk(n, B), B, 0, stream>>>(row_ptr, csr_src, perm, (const float2*)alS,
                                             (const float2*)alD, (float2*)eex, (float2*)selfw,
                                             (float2*)invden, n);
    k_gat_gather2_8<0><<<nblk((long long)n * 5, B), B, 0, stream>>>(
        (const uint4*)hbf, row_ptr, csr_src, perm, (const float2*)eex, (const float2*)selfw,
        (const float2*)invden, gat2_b, nullptr, (float4*)bufA, n, 5, 0);

    // ---- log_softmax -> d_out ----
    k_logsoftmax40<<<nblk(n, B), B, 0, stream>>>(bufA, out, n);
}

// Round 14
// 360.683 us; speedup vs baseline: 1.9358x; 1.9358x over previous
//
#include <hip/hip_runtime.h>
#include <math.h>

#define NNODES 50000
#define NEG_SLOPE 0.2f
#define BN_EPS 1e-5f

typedef __attribute__((ext_vector_type(8))) short bf16x8;
typedef __attribute__((ext_vector_type(4))) float f32x4;

static __device__ __forceinline__ float leaky(float x) {
    return x > 0.f ? x : NEG_SLOPE * x;
}
static __device__ __forceinline__ unsigned short f2bf(float x) {
    unsigned u = __float_as_uint(x);
    u += 0x7FFFu + ((u >> 16) & 1u);
    return (unsigned short)(u >> 16);
}
static __device__ __forceinline__ void unpack8(uint4 u, float* v) {
    v[0] = __uint_as_float(u.x << 16);
    v[1] = __uint_as_float(u.x & 0xFFFF0000u);
    v[2] = __uint_as_float(u.y << 16);
    v[3] = __uint_as_float(u.y & 0xFFFF0000u);
    v[4] = __uint_as_float(u.z << 16);
    v[5] = __uint_as_float(u.z & 0xFFFF0000u);
    v[6] = __uint_as_float(u.w << 16);
    v[7] = __uint_as_float(u.w & 0xFFFF0000u);
}
static __device__ __forceinline__ void acc8(uint4 u, float w, float* a) {
    float v[8]; unpack8(u, v);
#pragma unroll
    for (int j = 0; j < 8; ++j) a[j] = fmaf(w, v[j], a[j]);
}
static __device__ __forceinline__ void add8(uint4 u, float* a) {
    float v[8]; unpack8(u, v);
#pragma unroll
    for (int j = 0; j < 8; ++j) a[j] += v[j];
}
static __device__ __forceinline__ uint4 pack8(const float* o) {
    uint4 r;
    r.x = ((unsigned)f2bf(o[1]) << 16) | f2bf(o[0]);
    r.y = ((unsigned)f2bf(o[3]) << 16) | f2bf(o[2]);
    r.z = ((unsigned)f2bf(o[5]) << 16) | f2bf(o[4]);
    r.w = ((unsigned)f2bf(o[7]) << 16) | f2bf(o[6]);
    return r;
}

// ---------------- CSR build ----------------
__global__ void k_count(const int* __restrict__ dst, int* degi, int E) {
    int e = blockIdx.x * blockDim.x + threadIdx.x;
    if (e < E) atomicAdd(&degi[dst[e]], 1);
}
__global__ void k_scan1(const int* __restrict__ degi, int* __restrict__ incl,
                        int* __restrict__ bsum, int n) {
    __shared__ int s[256];
    int i = blockIdx.x * 256 + threadIdx.x;
    int v = (i < n) ? degi[i] : 0;
    s[threadIdx.x] = v;
    __syncthreads();
    for (int off = 1; off < 256; off <<= 1) {
        int t = (threadIdx.x >= (unsigned)off) ? s[threadIdx.x - off] : 0;
        __syncthreads();
        s[threadIdx.x] += t;
        __syncthreads();
    }
    if (i < n) incl[i] = s[threadIdx.x];
    if (threadIdx.x == 255) bsum[blockIdx.x] = s[255];
}
__global__ void k_scan2(int* bsum, int nb) {
    __shared__ int s[256];
    int v = ((int)threadIdx.x < nb) ? bsum[threadIdx.x] : 0;
    s[threadIdx.x] = v;
    __syncthreads();
    for (int off = 1; off < 256; off <<= 1) {
        int t = (threadIdx.x >= (unsigned)off) ? s[threadIdx.x - off] : 0;
        __syncthreads();
        s[threadIdx.x] += t;
        __syncthreads();
    }
    if ((int)threadIdx.x < nb) bsum[threadIdx.x] = s[threadIdx.x];
}
__global__ void k_scan3(const int* __restrict__ degi, const int* __restrict__ incl,
                        const int* __restrict__ bsum, int* __restrict__ row_ptr,
                        int* __restrict__ cursor, float* __restrict__ dinv, int n) {
    int i = blockIdx.x * 256 + threadIdx.x;
    if (i >= n) return;
    int off = (blockIdx.x > 0) ? bsum[blockIdx.x - 1] : 0;
    int inc = incl[i] + off;
    row_ptr[i + 1] = inc;
    cursor[i] = inc - degi[i];
    dinv[i] = rsqrtf((float)(degi[i] + 1));
    if (i == 0) row_ptr[0] = 0;
}
__global__ void k_fill(const int* __restrict__ src, const int* __restrict__ dst,
                       int* cursor, int* __restrict__ csr_src, int E) {
    int e = blockIdx.x * blockDim.x + threadIdx.x;
    if (e >= E) return;
    int pos = atomicAdd(&cursor[dst[e]], 1);
    csr_src[pos] = src[e];
}

// ---------------- fused conversions: x -> bf16, 4 weights -> bf16 transposed ----------------
__global__ void k_convall(const float4* __restrict__ x, uint4* __restrict__ xout,
                          const float* __restrict__ W1, unsigned short* __restrict__ w1T,
                          const float* __restrict__ W2, unsigned short* __restrict__ w2T,
                          const float* __restrict__ W3, unsigned short* __restrict__ w3T,
                          const float* __restrict__ W4, unsigned short* __restrict__ w4T,
                          int nx) {
    int i = blockIdx.x * blockDim.x + threadIdx.x;
    if (i < nx) {
        float4 a = x[i * 2], b = x[i * 2 + 1];
        float o[8] = {a.x, a.y, a.z, a.w, b.x, b.y, b.z, b.w};
        xout[i] = pack8(o);
        return;
    }
    int j = i - nx;
    if (j < 12288) {                       // W1 128x96
        int k = j / 96, c = j % 96;
        w1T[c * 128 + k] = f2bf(W1[j]);
    } else if ((j -= 12288) < 18432) {     // W2 96x192
        int k = j / 192, c = j % 192;
        w2T[c * 96 + k] = f2bf(W2[j]);
    } else if ((j -= 18432) < 9216) {      // W3 96x96
        int k = j / 96, c = j % 96;
        w3T[c * 96 + k] = f2bf(W3[j]);
    } else if ((j -= 9216) < 7680) {       // W4 96x80
        int k = j / 80, c = j % 80;
        w4T[c * 96 + k] = f2bf(W4[j]);
    }
}

// ---------------- MFMA bf16 GEMM ----------------
// HC>0: fused GAT logits epilogue. SCALE: multiply output row by dinv[row] (GCN pre-scale).
template<int KI, int KO, int HC, int SCALE>
__launch_bounds__(256)
__global__ void k_gemm_mfma(const unsigned short* __restrict__ A,
                            const unsigned short* __restrict__ WT,
                            unsigned short* __restrict__ C, int n,
                            const float* __restrict__ as, const float* __restrict__ ad,
                            float* __restrict__ alS, float* __restrict__ alD,
                            const float* __restrict__ dinv) {
    constexpr int KP = KI + 8;
    constexpr int NT = KO / 16;
    constexpr int KT = KI / 32;
    __shared__ unsigned short wT[KO][KP];
    const int t = threadIdx.x;
    const int w = t >> 6, l = t & 63;

    constexpr int CH = KI / 8;
    for (int idx = t; idx < KO * CH; idx += 256) {
        int r = idx / CH, o = idx % CH;
        *(uint4*)&wT[r][o * 8] = *(const uint4*)&WT[r * KI + o * 8];
    }
    int row = blockIdx.x * 64 + w * 16 + (l & 15);
    bool rv = row < n;
    const unsigned short* ap = A + (long long)row * KI + (l >> 4) * 8;
    bf16x8 afr[KT];
#pragma unroll
    for (int kt = 0; kt < KT; ++kt) {
        bf16x8 z = {};
        afr[kt] = rv ? *(const bf16x8*)(ap + kt * 32) : z;
    }
    __syncthreads();

    f32x4 acc[NT];
#pragma unroll
    for (int ct = 0; ct < NT; ++ct) acc[ct] = (f32x4){0.f, 0.f, 0.f, 0.f};
#pragma unroll
    for (int kt = 0; kt < KT; ++kt) {
#pragma unroll
        for (int ct = 0; ct < NT; ++ct) {
            bf16x8 b = *(const bf16x8*)&wT[ct * 16 + (l & 15)][kt * 32 + (l >> 4) * 8];
            acc[ct] = __builtin_amdgcn_mfma_f32_16x16x32_bf16(afr[kt], b, acc[ct], 0, 0, 0);
        }
    }
    int orow0 = blockIdx.x * 64 + w * 16 + (l >> 4) * 4;
    int col = l & 15;
    float dsc[4] = {1.f, 1.f, 1.f, 1.f};
    if (SCALE) {
#pragma unroll
        for (int r = 0; r < 4; ++r) {
            int rr = orow0 + r;
            if (rr < n) dsc[r] = dinv[rr];
        }
    }
#pragma unroll
    for (int ct = 0; ct < NT; ++ct) {
#pragma unroll
        for (int r = 0; r < 4; ++r) {
            int rr = orow0 + r;
            if (rr < n) C[(long long)rr * KO + ct * 16 + col] = f2bf(acc[ct][r] * dsc[r]);
        }
    }
    if (HC > 0) {
        float asv[NT], adv[NT];
#pragma unroll
        for (int ct = 0; ct < NT; ++ct) {
            int cg = ct * 16 + col;
            asv[ct] = as[cg];
            adv[ct] = ad[cg];
        }
#pragma unroll
        for (int r = 0; r < 4; ++r) {
            float s0 = 0.f, s1 = 0.f, d0 = 0.f, d1 = 0.f;
#pragma unroll
            for (int ct = 0; ct < NT; ++ct) {
                int cg = ct * 16 + col;
                float v = acc[ct][r];
                if (cg < HC) { s0 = fmaf(v, asv[ct], s0); d0 = fmaf(v, adv[ct], d0); }
                else         { s1 = fmaf(v, asv[ct], s1); d1 = fmaf(v, adv[ct], d1); }
            }
#pragma unroll
            for (int m = 1; m < 16; m <<= 1) {
                s0 += __shfl_xor(s0, m);
                s1 += __shfl_xor(s1, m);
                d0 += __shfl_xor(d0, m);
                d1 += __shfl_xor(d1, m);
            }
            int rr = orow0 + r;
            if ((l & 15) == 0 && rr < n) {
                alS[rr * 2] = s0; alS[rr * 2 + 1] = s1;
                alD[rr * 2] = d0; alD[rr * 2 + 1] = d1;
            }
        }
    }
}

// ---------------- GCN gather (pre-scaled bf16 table: pure sum) + bias + BN + relu ----------------
__global__ void k_gcn_gather_bn8(const uint4* __restrict__ hb, const int* __restrict__ row_ptr,
                                 const int* __restrict__ csr_src, const float* __restrict__ dinv,
                                 const float* __restrict__ bias, const float* __restrict__ g,
                                 const float* __restrict__ b, const float* __restrict__ m,
                                 const float* __restrict__ vv,
                                 uint4* __restrict__ outb, int n, int Q8) {
    int t = blockIdx.x * blockDim.x + threadIdx.x;
    if (t >= n * Q8) return;
    int v = t / Q8, q = t % Q8;
    int beg = row_ptr[v], end = row_ptr[v + 1];
    float dv = dinv[v];
    float a[8] = {0.f, 0.f, 0.f, 0.f, 0.f, 0.f, 0.f, 0.f};
    add8(hb[(long long)v * Q8 + q], a);  // self term (table pre-scaled by dinv)
    int p = beg;
    for (; p + 4 <= end; p += 4) {
        int s0 = csr_src[p], s1 = csr_src[p + 1], s2 = csr_src[p + 2], s3 = csr_src[p + 3];
        uint4 u0 = hb[(long long)s0 * Q8 + q];
        uint4 u1 = hb[(long long)s1 * Q8 + q];
        uint4 u2 = hb[(long long)s2 * Q8 + q];
        uint4 u3 = hb[(long long)s3 * Q8 + q];
        add8(u0, a);
        add8(u1, a);
        add8(u2, a);
        add8(u3, a);
    }
    for (; p < end; ++p) {
        int s = csr_src[p];
        add8(hb[(long long)s * Q8 + q], a);
    }
    int c0 = q * 8;
    float o[8];
#pragma unroll
    for (int j = 0; j < 8; ++j) {
        int c = c0 + j;
        float x = fmaf(a[j], dv, bias[c]);
        x = (x - m[c]) * rsqrtf(vv[c] + BN_EPS) * g[c] + b[c];
        o[j] = fmaxf(x, 0.f);
    }
    outb[(long long)v * Q8 + q] = pack8(o);
}

// ---------------- GAT softmax (two-pass, per node, both heads) ----------------
__global__ void k_gat_vh2p(const int* __restrict__ row_ptr, const int* __restrict__ csr_src,
                           const float2* __restrict__ alS2, const float2* __restrict__ alD2,
                           float2* __restrict__ eex2, float2* __restrict__ selfw2,
                           float2* __restrict__ invden2, int n) {
    int v = blockIdx.x * blockDim.x + threadIdx.x;
    if (v >= n) return;
    int beg = row_ptr[v], end = row_ptr[v + 1];
    float2 ad = alD2[v], as0 = alS2[v];
    float ls0 = leaky(as0.x + ad.x), ls1 = leaky(as0.y + ad.y);
    float m0 = ls0, m1 = ls1;
    int p = beg;
    for (; p + 2 <= end; p += 2) {
        int s0 = csr_src[p], s1 = csr_src[p + 1];
        float2 a0 = alS2[s0], a1 = alS2[s1];
        float l00 = leaky(a0.x + ad.x), l01 = leaky(a0.y + ad.y);
        float l10 = leaky(a1.x + ad.x), l11 = leaky(a1.y + ad.y);
        eex2[p] = make_float2(l00, l01);
        eex2[p + 1] = make_float2(l10, l11);
        m0 = fmaxf(m0, fmaxf(l00, l10));
        m1 = fmaxf(m1, fmaxf(l01, l11));
    }
    if (p < end) {
        int s = csr_src[p];
        float2 a = alS2[s];
        float l0 = leaky(a.x + ad.x), l1 = leaky(a.y + ad.y);
        eex2[p] = make_float2(l0, l1);
        m0 = fmaxf(m0, l0);
        m1 = fmaxf(m1, l1);
    }
    float e0 = expf(ls0 - m0), e1 = expf(ls1 - m1);
    float d0 = e0, d1 = e1;
    for (p = beg; p < end; ++p) {
        float2 l = eex2[p];
        float x0 = expf(l.x - m0), x1 = expf(l.y - m1);
        eex2[p] = make_float2(x0, x1);
        d0 += x0; d1 += x1;
    }
    selfw2[v] = make_float2(e0, e1);
    invden2[v] = make_float2(1.f / d0, 1.f / d1);
}
// ---------------- GAT gather (bf16, 4-edge unrolled) ----------------
template<int OUTBF>
__global__ void k_gat_gather2_8(const uint4* __restrict__ hb, const int* __restrict__ row_ptr,
                                const int* __restrict__ csr_src, const float2* __restrict__ eex2,
                                const float2* __restrict__ selfw2, const float2* __restrict__ invden2,
                                const float* __restrict__ bias, uint4* __restrict__ outb,
                                float4* __restrict__ outf, int n, int Q8, int do_relu) {
    int t = blockIdx.x * blockDim.x + threadIdx.x;
    if (t >= n * Q8) return;
    int v = t / Q8, q = t % Q8;
    int rowOct = 2 * Q8;
    int beg = row_ptr[v], end = row_ptr[v + 1];
    float A0[8] = {0,0,0,0,0,0,0,0}, A1[8] = {0,0,0,0,0,0,0,0};
    {
        float2 sw = selfw2[v];
        const uint4* hv = hb + (long long)v * rowOct;
        acc8(hv[q], sw.x, A0);
        acc8(hv[Q8 + q], sw.y, A1);
    }
    int p = beg;
    for (; p + 4 <= end; p += 4) {
        int s0 = csr_src[p], s1 = csr_src[p + 1], s2 = csr_src[p + 2], s3 = csr_src[p + 3];
        float2 w0 = eex2[p], w1 = eex2[p + 1], w2 = eex2[p + 2], w3 = eex2[p + 3];
        const uint4* h0 = hb + (long long)s0 * rowOct;
        const uint4* h1 = hb + (long long)s1 * rowOct;
        const uint4* h2 = hb + (long long)s2 * rowOct;
        const uint4* h3 = hb + (long long)s3 * rowOct;
        uint4 u00 = h0[q], u01 = h0[Q8 + q];
        uint4 u10 = h1[q], u11 = h1[Q8 + q];
        uint4 u20 = h2[q], u21 = h2[Q8 + q];
        uint4 u30 = h3[q], u31 = h3[Q8 + q];
        acc8(u00, w0.x, A0); acc8(u01, w0.y, A1);
        acc8(u10, w1.x, A0); acc8(u11, w1.y, A1);
        acc8(u20, w2.x, A0); acc8(u21, w2.y, A1);
        acc8(u30, w3.x, A0); acc8(u31, w3.y, A1);
    }
    for (; p < end; ++p) {
        int s = csr_src[p];
        float2 w = eex2[p];
        const uint4* hs = hb + (long long)s * rowOct;
        acc8(hs[q], w.x, A0);
        acc8(hs[Q8 + q], w.y, A1);
    }
    float2 idn = invden2[v];
    int c0 = q * 8;
    float o[8];
#pragma unroll
    for (int j = 0; j < 8; ++j) {
        float x = fmaf(0.5f, fmaf(A0[j], idn.x, A1[j] * idn.y), bias[c0 + j]);
        o[j] = do_relu ? fmaxf(x, 0.f) : x;
    }
    if (OUTBF) {
        outb[(long long)v * Q8 + q] = pack8(o);
    } else {
        long long ob = (long long)v * (Q8 * 2) + q * 2;
        outf[ob]     = make_float4(o[0], o[1], o[2], o[3]);
        outf[ob + 1] = make_float4(o[4], o[5], o[6], o[7]);
    }
}

__global__ void k_logsoftmax40(const float* __restrict__ in, float* __restrict__ out, int n) {
    int v = blockIdx.x * blockDim.x + threadIdx.x;
    if (v >= n) return;
    float vals[40];
    float mx = -INFINITY;
#pragma unroll
    for (int c = 0; c < 40; ++c) {
        float x = in[v * 40 + c];
        vals[c] = x;
        mx = fmaxf(mx, x);
    }
    float s = 0.f;
#pragma unroll
    for (int c = 0; c < 40; ++c) s += expf(vals[c] - mx);
    float ls = logf(s);
#pragma unroll
    for (int c = 0; c < 40; ++c) out[v * 40 + c] = vals[c] - mx - ls;
}

static inline int nblk(long long n, int b) { return (int)((n + b - 1) / b); }

extern "C" void kernel_launch(void* const* d_in, const int* in_sizes, int n_in,
                              void* d_out, int out_size, void* d_ws, size_t ws_size,
                              hipStream_t stream) {
    const float* x       = (const float*)d_in[0];
    const int*   ei      = (const int*)d_in[1];
    const float* gcn1_W  = (const float*)d_in[2];
    const float* gcn1_b  = (const float*)d_in[3];
    const float* bn1_g   = (const float*)d_in[4];
    const float* bn1_b   = (const float*)d_in[5];
    const float* bn1_m   = (const float*)d_in[6];
    const float* bn1_v   = (const float*)d_in[7];
    const float* gat1_W  = (const float*)d_in[8];
    const float* gat1_as = (const float*)d_in[9];
    const float* gat1_ad = (const float*)d_in[10];
    const float* gat1_b  = (const float*)d_in[11];
    const float* gcn2_W  = (const float*)d_in[12];
    const float* gcn2_b  = (const float*)d_in[13];
    const float* bn2_g   = (const float*)d_in[14];
    const float* bn2_b   = (const float*)d_in[15];
    const float* bn2_m   = (const float*)d_in[16];
    const float* bn2_v   = (const float*)d_in[17];
    const float* gat2_W  = (const float*)d_in[18];
    const float* gat2_as = (const float*)d_in[19];
    const float* gat2_ad = (const float*)d_in[20];
    const float* gat2_b  = (const float*)d_in[21];

    const int n = NNODES;
    const int E = in_sizes[1] / 2;
    const int* src = ei;
    const int* dst = ei + E;

    // ---- workspace carve (16B-aligned chunks) ----
    char* p = (char*)d_ws;
    float* dinv    = (float*)p; p += 50048 * 4;
    int*   degi    = (int*)p;   p += 50048 * 4;
    int*   row_ptr = (int*)p;   p += 50052 * 4;
    int*   cursor  = (int*)p;   p += 50048 * 4;
    int*   incl    = (int*)p;   p += 50048 * 4;
    int*   bsum    = (int*)p;   p += 256 * 4;
    int*   csr_src = (int*)p;   p += 800000 * 4;
    unsigned short* hbf = (unsigned short*)p; p += 9600000 * 2;  // bf16 h table [N,<=192]
    unsigned short* abf = (unsigned short*)p; p += 6400000 * 2;  // bf16 activations [N,<=128]
    unsigned short* wbf = (unsigned short*)p; p += 47616 * 2 + 64; // bf16 WT arena
    float* bufA    = (float*)p; p += 2000000 * 4;                // f32 gat2 out [N,40]
    float* alS     = (float*)p; p += 100096 * 4;
    float* alD     = (float*)p; p += 100096 * 4;
    float* selfw   = (float*)p; p += 100096 * 4;
    float* invden  = (float*)p; p += 100096 * 4;
    float* eex     = (float*)p; p += 1600000 * 4;                // float2[E]

    unsigned short* w1T = wbf;                 // [96][128]
    unsigned short* w2T = wbf + 12288;         // [192][96]
    unsigned short* w3T = wbf + 12288 + 18432; // [96][96]
    unsigned short* w4T = wbf + 12288 + 18432 + 9216; // [80][96]

    const int B = 256;
    const int GB = nblk(n, 64);
    const int SB = nblk(n, 256);
    float* out = (float*)d_out;

    // ---- fused conversions (x + 4 weights) ----
    const int NX = n * 16;
    k_convall<<<nblk(NX + 47616, B), B, 0, stream>>>(
        (const float4*)x, (uint4*)abf, gcn1_W, w1T, gat1_W, w2T, gcn2_W, w3T, gat2_W, w4T, NX);

    // ---- CSR build ----
    hipMemsetAsync(degi, 0, (size_t)n * 4, stream);
    k_count<<<nblk(E, B), B, 0, stream>>>(dst, degi, E);
    k_scan1<<<SB, 256, 0, stream>>>(degi, incl, bsum, n);
    k_scan2<<<1, 256, 0, stream>>>(bsum, SB);
    k_scan3<<<SB, 256, 0, stream>>>(degi, incl, bsum, row_ptr, cursor, dinv, n);
    k_fill<<<nblk(E, B), B, 0, stream>>>(src, dst, cursor, csr_src, E);

    // ---- GCN1 (GEMM pre-scales rows by dinv; gather is pure sum) ----
    k_gemm_mfma<128, 96, 0, 1><<<GB, 256, 0, stream>>>(abf, w1T, hbf, n, nullptr, nullptr,
                                                       nullptr, nullptr, dinv);
    k_gcn_gather_bn8<<<nblk((long long)n * 12, B), B, 0, stream>>>(
        (const uint4*)hbf, row_ptr, csr_src, dinv, gcn1_b, bn1_g, bn1_b, bn1_m, bn1_v,
        (uint4*)abf, n, 12);

    // ---- GAT1 (logits fused into GEMM epilogue) ----
    k_gemm_mfma<96, 192, 96, 0><<<GB, 256, 0, stream>>>(abf, w2T, hbf, n, gat1_as, gat1_ad,
                                                        alS, alD, nullptr);
    k_gat_vh2p<<<nblk(n, B), B, 0, stream>>>(row_ptr, csr_src, (const float2*)alS, (const float2*)alD,
                                             (float2*)eex, (float2*)selfw, (float2*)invden, n);
    k_gat_gather2_8<1><<<nblk((long long)n * 12, B), B, 0, stream>>>(
        (const uint4*)hbf, row_ptr, csr_src, (const float2*)eex, (const float2*)selfw,
        (const float2*)invden, gat1_b, (uint4*)abf, nullptr, n, 12, 1);

    // ---- GCN2 ----
    k_gemm_mfma<96, 96, 0, 1><<<GB, 256, 0, stream>>>(abf, w3T, hbf, n, nullptr, nullptr,
                                                      nullptr, nullptr, dinv);
    k_gcn_gather_bn8<<<nblk((long long)n * 12, B), B, 0, stream>>>(
        (const uint4*)hbf, row_ptr, csr_src, dinv, gcn2_b, bn2_g, bn2_b, bn2_m, bn2_v,
        (uint4*)abf, n, 12);

    // ---- GAT2 (logits fused) ----
    k_gemm_mfma<96, 80, 40, 0><<<GB, 256, 0, stream>>>(abf, w4T, hbf, n, gat2_as, gat2_ad,
                                                       alS, alD, nullptr);
    k_gat_vh2p<<<nblk(n, B), B, 0, stream>>>(row_ptr, csr_src, (const float2*)alS, (const float2*)alD,
                                             (float2*)eex, (float2*)selfw, (float2*)invden, n);
    k_gat_gather2_8<0><<<nblk((long long)n * 5, B), B, 0, stream>>>(
        (const uint4*)hbf, row_ptr, csr_src, (const float2*)eex, (const float2*)selfw,
        (const float2*)invden, gat2_b, nullptr, (float4*)bufA, n, 5, 0);

    // ---- log_softmax -> d_out ----
    k_logsoftmax40<<<nblk(n, B), B, 0, stream>>>(bufA, out, n);
}